// Round 12
// baseline (127.712 us; speedup 1.0000x reference)
//
#include <hip/hip_runtime.h>
#include <hip/hip_bf16.h>

#define D 128
#define PROWS 64
#define CAP 2048           // slot capacity per partition (mean 1024)
#define NPART_MAX 2048
#define NB 256             // coarse radix buckets
#define BCAP 8192          // bucket capacity (mean 6250)
#define EPT1 6             // edges/thread pass 1 (1024-thr blocks)

typedef __attribute__((ext_vector_type(8))) short short8;
typedef __attribute__((ext_vector_type(4))) float f32x4;

__device__ __forceinline__ short f2bf(float f) {
  __hip_bfloat16 h = __float2bfloat16(f);
  return (short)*reinterpret_cast<unsigned short*>(&h);
}
__device__ __forceinline__ float bf2f(unsigned short u) {
  union { unsigned i; float f; } x;
  x.i = ((unsigned)u) << 16;
  return x.f;
}

// ---------------------------------------------------------------------------
// Prep: W -> W2 (bf16) + zero bucket cursors.
// ---------------------------------------------------------------------------
__global__ __launch_bounds__(256) void prep_kernel(
    const float* __restrict__ W, unsigned short* __restrict__ W2,
    int* __restrict__ bcur) {
  int i = blockIdx.x * 256 + threadIdx.x;
  if (i < D * D) W2[i] = (unsigned short)f2bf(W[i]);
  if (i < NB) bcur[i] = 0;
}

// ---------------------------------------------------------------------------
// Radix pass 1: bin edges into NB coarse buckets (chunk-claimed, ~192B/chunk
// -> near-full-line writes). Payload: col | rl<<17 | pib<<23.
// ---------------------------------------------------------------------------
__global__ __launch_bounds__(1024) void radix_p1_kernel(
    const int* __restrict__ rows, const int* __restrict__ cols,
    const float* __restrict__ vals, int* __restrict__ bcur,
    float2* __restrict__ breg, int E, int ppb, int pmagic) {
  __shared__ int cnt[NB];
  __shared__ int bas[NB];
  const int t = threadIdx.x;
  if (t < NB) cnt[t] = 0;
  __syncthreads();
  int base = blockIdx.x * (1024 * EPT1);
#pragma unroll
  for (int k = 0; k < EPT1; ++k) {
    int idx = base + k * 1024 + t;
    if (idx < E) {
      int p = rows[idx] >> 6;
      int b = (p * pmagic) >> 16;
      atomicAdd(&cnt[b], 1);
    }
  }
  __syncthreads();
  if (t < NB) {
    int c = cnt[t];
    bas[t] = c ? atomicAdd(&bcur[t], c) : 0;
    cnt[t] = 0;
  }
  __syncthreads();
#pragma unroll
  for (int k = 0; k < EPT1; ++k) {
    int idx = base + k * 1024 + t;
    if (idx < E) {
      int r = rows[idx];
      int p = r >> 6;
      int b = (p * pmagic) >> 16;
      int pib = p - b * ppb;
      int rank = atomicAdd(&cnt[b], 1);
      int off = bas[b] + rank;
      if (off < BCAP) {  // statistical overflow guard
        float2 m;
        m.x = __int_as_float(cols[idx] | ((r & 63) << 17) | (pib << 23));
        m.y = vals[idx];
        breg[(size_t)b * BCAP + off] = m;
      }
    }
  }
}

// ---------------------------------------------------------------------------
// Radix pass 2 with wave-ballot aggregation: one block per bucket; route
// edges to the <=8 partitions it owns. Per 64-edge wave iteration: 8 ballots,
// ONE LDS atomic per (wave, bin) instead of per edge (64x less same-address
// serialization). Rank = base + popc(mask & lanemask_lt).
// ---------------------------------------------------------------------------
__global__ __launch_bounds__(1024) void radix_p2_kernel(
    const float2* __restrict__ breg, const int* __restrict__ bcur,
    float2* __restrict__ slots, int* __restrict__ cursor, int npart, int ppb) {
  __shared__ int cnt[8];
  const int b = blockIdx.x, t = threadIdx.x;
  const int lane = t & 63;
  if (t < 8) cnt[t] = 0;
  __syncthreads();
  int ne = bcur[b];
  if (ne > BCAP) ne = BCAP;
  const float2* src = breg + (size_t)b * BCAP;
  const unsigned long long ltmask = (1ULL << lane) - 1;

  for (int j0 = 0; j0 < ne; j0 += 1024) {
    int j = j0 + t;
    bool valid = j < ne;
    float2 m;
    m.x = 0.f;
    m.y = 0.f;
    if (valid) m = src[j];
    int pib = valid ? ((__float_as_int(m.x) >> 23) & 7) : -1;
    int myoff = CAP;  // sentinel (skips store)
    int myp = 0;
#pragma unroll
    for (int bb = 0; bb < 8; ++bb) {
      unsigned long long mask = __ballot(pib == bb);
      if (mask) {  // wave-uniform
        int leader = (int)__ffsll((unsigned long long)mask) - 1;
        int base = 0;
        if (lane == leader) base = atomicAdd(&cnt[bb], (int)__popcll(mask));
        base = __shfl(base, leader, 64);
        if (pib == bb) {
          myoff = base + (int)__popcll(mask & ltmask);
          myp = b * ppb + bb;
        }
      }
    }
    if (valid && myoff < CAP) slots[(size_t)myp * CAP + myoff] = m;
  }
  __syncthreads();
  if (t < ppb) {
    int p = b * ppb + t;
    if (p < npart) cursor[p] = cnt[t] < CAP ? cnt[t] : CAP;
  }
}

// ---------------------------------------------------------------------------
// GEMM MFMA bf16 (proven inner loop) + LDS-repacked coalesced bf16 stores.
// ---------------------------------------------------------------------------
__global__ __launch_bounds__(256) void gemm_mfma_bf16_kernel(
    const float* __restrict__ emb, const unsigned short* __restrict__ W2,
    unsigned short* __restrict__ H2, int N) {
  __shared__ short8 WldsV[2048];  // 32 KB
  char* Wlds = (char*)WldsV;
  const int tid = threadIdx.x;

  for (int i = tid; i < 128 * 16; i += 256) {
    int o = i >> 4, dblk = i & 15;
    short8 u = *(const short8*)(W2 + (size_t)o * D + dblk * 8);  // coalesced
    *(short8*)(Wlds + o * 256 + ((dblk ^ (o & 7)) << 4)) = u;
  }
  __syncthreads();

  const int w = tid >> 6, l = tid & 63;
  const int lo = l & 15, hi = l >> 4;
  const int mbase = blockIdx.x * 64 + w * 16;

  int arow = mbase + lo;
  if (arow >= N) arow = N - 1;  // clamp; stores guarded
  const float* ap = emb + (size_t)arow * D + hi * 8;

  float4 a0[4], a1[4];
#pragma unroll
  for (int kb = 0; kb < 4; ++kb) {
    a0[kb] = *(const float4*)(ap + kb * 32);
    a1[kb] = *(const float4*)(ap + kb * 32 + 4);
  }

  f32x4 acc[8];
#pragma unroll
  for (int ot = 0; ot < 8; ++ot) acc[ot] = (f32x4){0.f, 0.f, 0.f, 0.f};

  const char* brow = Wlds + lo * 256;
#pragma unroll
  for (int kb = 0; kb < 4; ++kb) {
    short8 av;
    av[0] = f2bf(a0[kb].x); av[1] = f2bf(a0[kb].y);
    av[2] = f2bf(a0[kb].z); av[3] = f2bf(a0[kb].w);
    av[4] = f2bf(a1[kb].x); av[5] = f2bf(a1[kb].y);
    av[6] = f2bf(a1[kb].z); av[7] = f2bf(a1[kb].w);
    const int xb = (((kb << 2) | hi) ^ (l & 7)) << 4;
#pragma unroll
    for (int ot = 0; ot < 8; ++ot) {
      short8 bv = *(const short8*)(brow + ot * 4096 + xb);
      acc[ot] = __builtin_amdgcn_mfma_f32_16x16x32_bf16(av, bv, acc[ot], 0, 0, 0);
    }
  }

  // Epilogue: all waves done reading Wlds -> reuse as output staging.
  __syncthreads();
  unsigned short* st = (unsigned short*)(Wlds + (w << 12));  // 4 KB/wave
#pragma unroll
  for (int r = 0; r < 4; ++r)
#pragma unroll
    for (int ot = 0; ot < 8; ++ot)
      st[(hi * 4 + r) * 128 + ot * 16 + lo] = (unsigned short)f2bf(acc[ot][r]);

  short8* dst = (short8*)(H2 + (size_t)mbase * D);
  const short8* src = (const short8*)st;
#pragma unroll
  for (int q = 0; q < 4; ++q) {
    int idx = l + 64 * q;          // 256 short8 = 16 rows x 16
    int row = idx >> 4;
    if (mbase + row < N) dst[idx] = src[idx];
  }
}

// ---------------------------------------------------------------------------
// Fused sort+gather SpMM (byte-roofline'd, unchanged).
// ---------------------------------------------------------------------------
__global__ __launch_bounds__(256) void spmm_part_kernel(
    const unsigned short* __restrict__ H2, const int* __restrict__ cursor,
    const float2* __restrict__ slots, float* __restrict__ out, int N) {
  __shared__ float2 sorted[CAP];
  __shared__ int cnt[PROWS];
  __shared__ int rowofs[PROWS];
  __shared__ int cnt2[PROWS];

  int p = blockIdx.x;
  int t = threadIdx.x;
  const float2* slice = slots + (size_t)p * CAP;
  int ne = cursor[p];
  if (ne > CAP) ne = CAP;

  if (t < PROWS) { cnt[t] = 0; cnt2[t] = 0; }
  __syncthreads();

  float2 my[CAP / 256];
#pragma unroll
  for (int k = 0; k < CAP / 256; ++k) {
    int j = t + k * 256;
    if (j < ne) {
      my[k] = slice[j];
      atomicAdd(&cnt[(__float_as_int(my[k].x) >> 17) & 63], 1);
    }
  }
  __syncthreads();

  if (t < 64) {
    int v = cnt[t];
    int x = v;
#pragma unroll
    for (int dd = 1; dd < 64; dd <<= 1) {
      int y = __shfl_up(x, dd, 64);
      if (t >= dd) x += y;
    }
    rowofs[t] = x - v;
  }
  __syncthreads();

#pragma unroll
  for (int k = 0; k < CAP / 256; ++k) {
    int j = t + k * 256;
    if (j < ne) {
      int rl = (__float_as_int(my[k].x) >> 17) & 63;
      int rank = atomicAdd(&cnt2[rl], 1);
      sorted[rowofs[rl] + rank] = my[k];
    }
  }
  __syncthreads();

  int w = t >> 6, l = t & 63;
  for (int rr = 0; rr < 16; ++rr) {
    int rl = w * 16 + rr;
    int row = p * PROWS + rl;
    if (row >= N) break;  // wave-uniform
    int s = rowofs[rl];
    int e = s + cnt[rl];
    float ax = 0.f, ay = 0.f;
    int j = s;
    for (; j + 4 <= e; j += 4) {
      float2 m0 = sorted[j];
      float2 m1 = sorted[j + 1];
      float2 m2 = sorted[j + 2];
      float2 m3 = sorted[j + 3];
      int c0 = __float_as_int(m0.x) & 0x1FFFF;
      int c1 = __float_as_int(m1.x) & 0x1FFFF;
      int c2 = __float_as_int(m2.x) & 0x1FFFF;
      int c3 = __float_as_int(m3.x) & 0x1FFFF;
      ushort2 x0 = *(const ushort2*)(H2 + (size_t)c0 * D + 2 * l);
      ushort2 x1 = *(const ushort2*)(H2 + (size_t)c1 * D + 2 * l);
      ushort2 x2 = *(const ushort2*)(H2 + (size_t)c2 * D + 2 * l);
      ushort2 x3 = *(const ushort2*)(H2 + (size_t)c3 * D + 2 * l);
      ax = fmaf(m0.y, bf2f(x0.x), ax); ay = fmaf(m0.y, bf2f(x0.y), ay);
      ax = fmaf(m1.y, bf2f(x1.x), ax); ay = fmaf(m1.y, bf2f(x1.y), ay);
      ax = fmaf(m2.y, bf2f(x2.x), ax); ay = fmaf(m2.y, bf2f(x2.y), ay);
      ax = fmaf(m3.y, bf2f(x3.x), ax); ay = fmaf(m3.y, bf2f(x3.y), ay);
    }
    for (; j < e; ++j) {
      float2 m = sorted[j];
      int c = __float_as_int(m.x) & 0x1FFFF;
      ushort2 x = *(const ushort2*)(H2 + (size_t)c * D + 2 * l);
      ax = fmaf(m.y, bf2f(x.x), ax); ay = fmaf(m.y, bf2f(x.y), ay);
    }
    ax = ax >= 0.f ? ax : 0.2f * ax;
    ay = ay >= 0.f ? ay : 0.2f * ay;
    float2 o;
    o.x = ax;
    o.y = ay;
    ((float2*)(out + (size_t)row * D))[l] = o;
  }
}

// ---------------------------------------------------------------------------
// Fallback path (fp32 H + atomic scatter) if workspace/shape limits exceeded.
// ---------------------------------------------------------------------------
__global__ __launch_bounds__(256) void gemm_mfma_f32_kernel(
    const float* __restrict__ emb, const float* __restrict__ W,
    float* __restrict__ H, int N) {
  __shared__ short8 WldsV[2048];
  char* Wlds = (char*)WldsV;
  const int tid = threadIdx.x;
  for (int i = tid; i < 128 * 16; i += 256) {
    int o = i >> 4, dblk = i & 15;
    const float* wp = W + o * D + dblk * 8;
    float4 f0 = *(const float4*)wp;
    float4 f1 = *(const float4*)(wp + 4);
    short8 u;
    u[0] = f2bf(f0.x); u[1] = f2bf(f0.y); u[2] = f2bf(f0.z); u[3] = f2bf(f0.w);
    u[4] = f2bf(f1.x); u[5] = f2bf(f1.y); u[6] = f2bf(f1.z); u[7] = f2bf(f1.w);
    *(short8*)(Wlds + o * 256 + ((dblk ^ (o & 7)) << 4)) = u;
  }
  __syncthreads();
  const int w = tid >> 6, l = tid & 63;
  const int lo = l & 15, hi = l >> 4;
  const int mbase = blockIdx.x * 64 + w * 16;
  int arow = mbase + lo;
  if (arow >= N) arow = N - 1;
  const float* ap = emb + (size_t)arow * D + hi * 8;
  float4 a0[4], a1[4];
#pragma unroll
  for (int kb = 0; kb < 4; ++kb) {
    a0[kb] = *(const float4*)(ap + kb * 32);
    a1[kb] = *(const float4*)(ap + kb * 32 + 4);
  }
  f32x4 acc[8];
#pragma unroll
  for (int ot = 0; ot < 8; ++ot) acc[ot] = (f32x4){0.f, 0.f, 0.f, 0.f};
  const char* brow = Wlds + lo * 256;
#pragma unroll
  for (int kb = 0; kb < 4; ++kb) {
    short8 av;
    av[0] = f2bf(a0[kb].x); av[1] = f2bf(a0[kb].y);
    av[2] = f2bf(a0[kb].z); av[3] = f2bf(a0[kb].w);
    av[4] = f2bf(a1[kb].x); av[5] = f2bf(a1[kb].y);
    av[6] = f2bf(a1[kb].z); av[7] = f2bf(a1[kb].w);
    const int xb = (((kb << 2) | hi) ^ (l & 7)) << 4;
#pragma unroll
    for (int ot = 0; ot < 8; ++ot) {
      short8 bv = *(const short8*)(brow + ot * 4096 + xb);
      acc[ot] = __builtin_amdgcn_mfma_f32_16x16x32_bf16(av, bv, acc[ot], 0, 0, 0);
    }
  }
  const int rowout = mbase + hi * 4;
#pragma unroll
  for (int r = 0; r < 4; ++r) {
    int ro = rowout + r;
    if (ro < N) {
      float* op = H + (size_t)ro * D + lo;
#pragma unroll
      for (int ot = 0; ot < 8; ++ot) op[ot * 16] = acc[ot][r];
    }
  }
}

__global__ __launch_bounds__(256) void spmm_scatter_kernel(
    const float* __restrict__ H, const int* __restrict__ rows,
    const int* __restrict__ cols, const float* __restrict__ vals,
    float* __restrict__ out, int E) {
  long long gid = (long long)blockIdx.x * blockDim.x + threadIdx.x;
  int e = (int)(gid >> 5);
  int l = (int)(gid & 31);
  if (e >= E) return;
  int r = rows[e];
  int c = cols[e];
  float v = vals[e];
  float4 h4 = ((const float4*)(H + (size_t)c * D))[l];
  float* op = out + (size_t)r * D + l * 4;
  atomicAdd(op + 0, v * h4.x);
  atomicAdd(op + 1, v * h4.y);
  atomicAdd(op + 2, v * h4.z);
  atomicAdd(op + 3, v * h4.w);
}

__global__ __launch_bounds__(256) void leaky_kernel(float* __restrict__ out,
                                                    int n4) {
  for (int i = blockIdx.x * blockDim.x + threadIdx.x; i < n4;
       i += gridDim.x * blockDim.x) {
    float4 v = ((const float4*)out)[i];
    v.x = v.x >= 0.f ? v.x : 0.2f * v.x;
    v.y = v.y >= 0.f ? v.y : 0.2f * v.y;
    v.z = v.z >= 0.f ? v.z : 0.2f * v.z;
    v.w = v.w >= 0.f ? v.w : 0.2f * v.w;
    ((float4*)out)[i] = v;
  }
}

extern "C" void kernel_launch(void* const* d_in, const int* in_sizes, int n_in,
                              void* d_out, int out_size, void* d_ws,
                              size_t ws_size, hipStream_t stream) {
  const float* emb  = (const float*)d_in[0];
  const float* W    = (const float*)d_in[1];
  const int*   rows = (const int*)d_in[2];
  const int*   cols = (const int*)d_in[3];
  const float* vals = (const float*)d_in[4];
  float* out = (float*)d_out;

  int N = in_sizes[0] / D;
  int E = in_sizes[2];
  int npart = (N + PROWS - 1) / PROWS;
  int ppb = (npart + NB - 1) / NB;              // partitions per bucket (<=8)
  int pmagic = (65536 + ppb - 1) / ppb;         // exact /ppb for p<2048

  char* p = (char*)d_ws;
  auto carve = [&](size_t bytes) {
    char* r = p;
    p += (bytes + 255) & ~(size_t)255;
    return r;
  };
  unsigned short* H2     = (unsigned short*)carve((size_t)N * D * 2);
  unsigned short* W2     = (unsigned short*)carve((size_t)D * D * 2);
  int*            bcur   = (int*)carve((size_t)NB * sizeof(int));
  int*            cursor = (int*)carve((size_t)npart * sizeof(int));
  float2*         breg   = (float2*)carve((size_t)NB * BCAP * sizeof(float2));
  float2*         slots  = (float2*)carve((size_t)npart * CAP * sizeof(float2));
  size_t needed = (size_t)(p - (char*)d_ws);

  int gblocks = (N + 63) / 64;
  int p1_blocks = (E + 1024 * EPT1 - 1) / (1024 * EPT1);

  if (needed <= ws_size && npart <= NPART_MAX && N <= (1 << 17)) {
    prep_kernel<<<(D * D + 255) / 256, 256, 0, stream>>>(W, W2, bcur);
    radix_p1_kernel<<<p1_blocks, 1024, 0, stream>>>(rows, cols, vals, bcur,
                                                    breg, E, ppb, pmagic);
    radix_p2_kernel<<<NB, 1024, 0, stream>>>(breg, bcur, slots, cursor, npart,
                                             ppb);
    gemm_mfma_bf16_kernel<<<gblocks, 256, 0, stream>>>(emb, W2, H2, N);
    spmm_part_kernel<<<npart, 256, 0, stream>>>(H2, cursor, slots, out, N);
  } else {
    float* Hf = (float*)d_ws;
    gemm_mfma_f32_kernel<<<gblocks, 256, 0, stream>>>(emb, W, Hf, N);
    hipMemsetAsync(d_out, 0, (size_t)N * D * sizeof(float), stream);
    long long sthreads = (long long)E * 32;
    int sblocks = (int)((sthreads + 255) / 256);
    spmm_scatter_kernel<<<sblocks, 256, 0, stream>>>(Hf, rows, cols, vals, out, E);
    leaky_kernel<<<1024, 256, 0, stream>>>(out, N * D / 4);
  }
}

// Round 13
// 114.874 us; speedup vs baseline: 1.1118x; 1.1118x over previous
//
#include <hip/hip_runtime.h>
#include <hip/hip_bf16.h>

#define D 128
#define PROWS 64
#define CAP 2048           // slot capacity per partition (mean 1024)
#define NPART_MAX 2048
#define PASSA_EPT 24

typedef __attribute__((ext_vector_type(8))) short short8;
typedef __attribute__((ext_vector_type(4))) float f32x4;

__device__ __forceinline__ short f2bf(float f) {
  __hip_bfloat16 h = __float2bfloat16(f);
  return (short)*reinterpret_cast<unsigned short*>(&h);
}
__device__ __forceinline__ float bf2f(unsigned short u) {
  union { unsigned i; float f; } x;
  x.i = ((unsigned)u) << 16;
  return x.f;
}

// ---------------------------------------------------------------------------
// Prep: W (fp32, 128x128) -> W2 (bf16, global) + cursor = 0.
// ---------------------------------------------------------------------------
__global__ __launch_bounds__(256) void prep_kernel(
    const float* __restrict__ W, unsigned short* __restrict__ W2,
    int* __restrict__ cursor, int npart) {
  int i = blockIdx.x * 256 + threadIdx.x;
  if (i < D * D) W2[i] = (unsigned short)f2bf(W[i]);
  if (i < npart) cursor[i] = 0;
}

// ---------------------------------------------------------------------------
// Fused heterogeneous dispatch (r8 proven-best structure):
//   blockIdx <  nb_edge : partition scatter (chunk-claimed merged writes)
//   blockIdx >= nb_edge : GEMM tile (MFMA bf16, W2->LDS staging) + r11's
//                         LDS-repacked coalesced epilogue stores.
// ---------------------------------------------------------------------------
__global__ __launch_bounds__(256) void fused_gemm_scatter_kernel(
    const float* __restrict__ emb, const unsigned short* __restrict__ W2,
    unsigned short* __restrict__ H2, const int* __restrict__ rows,
    const int* __restrict__ cols, const float* __restrict__ vals,
    int* __restrict__ cursor, float2* __restrict__ slots,
    int E, int N, int npart, int nb_edge) {
  __shared__ int smem[8192];  // 32 KB union
  const int tid = threadIdx.x;

  if ((int)blockIdx.x < nb_edge) {
    // ---------------- scatter role (r6/r8 proven) ----------------
    int* cnt = smem;            // [NPART_MAX]
    int* bas = smem + NPART_MAX;
    for (int i = tid; i < npart; i += 256) cnt[i] = 0;
    __syncthreads();
    int base = blockIdx.x * (256 * PASSA_EPT);
#pragma unroll
    for (int k = 0; k < PASSA_EPT; ++k) {
      int idx = base + k * 256 + tid;
      if (idx < E) atomicAdd(&cnt[rows[idx] >> 6], 1);
    }
    __syncthreads();
    for (int i = tid; i < npart; i += 256) {
      int c = cnt[i];
      bas[i] = c ? atomicAdd(&cursor[i], c) : 0;
      cnt[i] = 0;
    }
    __syncthreads();
#pragma unroll
    for (int k = 0; k < PASSA_EPT; ++k) {
      int idx = base + k * 256 + tid;
      if (idx < E) {
        int r = rows[idx];
        int p = r >> 6;
        int rank = atomicAdd(&cnt[p], 1);
        int off = bas[p] + rank;
        if (off < CAP) {  // overflow guard
          float2 m;
          m.x = __int_as_float(cols[idx] | ((r & 63) << 17));
          m.y = vals[idx];
          slots[(size_t)p * CAP + off] = m;
        }
      }
    }
  } else {
    // ---------------- gemm role (r5/r8 inner loop + r11 epilogue) --------
    int bid = blockIdx.x - nb_edge;
    char* Wlds = (char*)smem;  // 32 KB
    for (int i = tid; i < 128 * 16; i += 256) {
      int o = i >> 4, dblk = i & 15;
      short8 u = *(const short8*)(W2 + (size_t)o * D + dblk * 8);  // coalesced
      *(short8*)(Wlds + o * 256 + ((dblk ^ (o & 7)) << 4)) = u;
    }
    __syncthreads();

    const int w = tid >> 6, l = tid & 63;
    const int lo = l & 15, hi = l >> 4;
    const int mbase = bid * 64 + w * 16;

    int arow = mbase + lo;
    if (arow >= N) arow = N - 1;  // clamp; stores guarded
    const float* ap = emb + (size_t)arow * D + hi * 8;

    float4 a0[4], a1[4];
#pragma unroll
    for (int kb = 0; kb < 4; ++kb) {
      a0[kb] = *(const float4*)(ap + kb * 32);
      a1[kb] = *(const float4*)(ap + kb * 32 + 4);
    }

    f32x4 acc[8];
#pragma unroll
    for (int ot = 0; ot < 8; ++ot) acc[ot] = (f32x4){0.f, 0.f, 0.f, 0.f};

    const char* brow = Wlds + lo * 256;
#pragma unroll
    for (int kb = 0; kb < 4; ++kb) {
      short8 av;
      av[0] = f2bf(a0[kb].x); av[1] = f2bf(a0[kb].y);
      av[2] = f2bf(a0[kb].z); av[3] = f2bf(a0[kb].w);
      av[4] = f2bf(a1[kb].x); av[5] = f2bf(a1[kb].y);
      av[6] = f2bf(a1[kb].z); av[7] = f2bf(a1[kb].w);
      const int xb = (((kb << 2) | hi) ^ (l & 7)) << 4;
#pragma unroll
      for (int ot = 0; ot < 8; ++ot) {
        short8 bv = *(const short8*)(brow + ot * 4096 + xb);
        acc[ot] = __builtin_amdgcn_mfma_f32_16x16x32_bf16(av, bv, acc[ot], 0, 0, 0);
      }
    }

    // Epilogue: all waves done reading Wlds -> reuse as output staging,
    // then 16B coalesced stores (vs 32x 2B scattered per lane).
    __syncthreads();
    unsigned short* st = (unsigned short*)(Wlds + (w << 12));  // 4 KB/wave
#pragma unroll
    for (int r = 0; r < 4; ++r)
#pragma unroll
      for (int ot = 0; ot < 8; ++ot)
        st[(hi * 4 + r) * 128 + ot * 16 + lo] = (unsigned short)f2bf(acc[ot][r]);

    short8* dst = (short8*)(H2 + (size_t)mbase * D);
    const short8* src = (const short8*)st;
#pragma unroll
    for (int q = 0; q < 4; ++q) {
      int idx = l + 64 * q;          // 256 short8 = 16 rows x 16
      int row = idx >> 4;
      if (mbase + row < N) dst[idx] = src[idx];
    }
  }
}

// ---------------------------------------------------------------------------
// Fused sort+gather SpMM (byte-roofline'd, 6x confirmed): one block/partition.
// ---------------------------------------------------------------------------
__global__ __launch_bounds__(256) void spmm_part_kernel(
    const unsigned short* __restrict__ H2, const int* __restrict__ cursor,
    const float2* __restrict__ slots, float* __restrict__ out, int N) {
  __shared__ float2 sorted[CAP];
  __shared__ int cnt[PROWS];
  __shared__ int rowofs[PROWS];
  __shared__ int cnt2[PROWS];

  int p = blockIdx.x;
  int t = threadIdx.x;
  const float2* slice = slots + (size_t)p * CAP;
  int ne = cursor[p];
  if (ne > CAP) ne = CAP;

  if (t < PROWS) { cnt[t] = 0; cnt2[t] = 0; }
  __syncthreads();

  float2 my[CAP / 256];
#pragma unroll
  for (int k = 0; k < CAP / 256; ++k) {
    int j = t + k * 256;
    if (j < ne) {
      my[k] = slice[j];
      atomicAdd(&cnt[(__float_as_int(my[k].x) >> 17) & 63], 1);
    }
  }
  __syncthreads();

  if (t < 64) {
    int v = cnt[t];
    int x = v;
#pragma unroll
    for (int dd = 1; dd < 64; dd <<= 1) {
      int y = __shfl_up(x, dd, 64);
      if (t >= dd) x += y;
    }
    rowofs[t] = x - v;
  }
  __syncthreads();

#pragma unroll
  for (int k = 0; k < CAP / 256; ++k) {
    int j = t + k * 256;
    if (j < ne) {
      int rl = (__float_as_int(my[k].x) >> 17) & 63;
      int rank = atomicAdd(&cnt2[rl], 1);
      sorted[rowofs[rl] + rank] = my[k];
    }
  }
  __syncthreads();

  int w = t >> 6, l = t & 63;
  for (int rr = 0; rr < 16; ++rr) {
    int rl = w * 16 + rr;
    int row = p * PROWS + rl;
    if (row >= N) break;  // wave-uniform
    int s = rowofs[rl];
    int e = s + cnt[rl];
    float ax = 0.f, ay = 0.f;
    int j = s;
    for (; j + 4 <= e; j += 4) {
      float2 m0 = sorted[j];
      float2 m1 = sorted[j + 1];
      float2 m2 = sorted[j + 2];
      float2 m3 = sorted[j + 3];
      int c0 = __float_as_int(m0.x) & 0x1FFFF;
      int c1 = __float_as_int(m1.x) & 0x1FFFF;
      int c2 = __float_as_int(m2.x) & 0x1FFFF;
      int c3 = __float_as_int(m3.x) & 0x1FFFF;
      ushort2 x0 = *(const ushort2*)(H2 + (size_t)c0 * D + 2 * l);
      ushort2 x1 = *(const ushort2*)(H2 + (size_t)c1 * D + 2 * l);
      ushort2 x2 = *(const ushort2*)(H2 + (size_t)c2 * D + 2 * l);
      ushort2 x3 = *(const ushort2*)(H2 + (size_t)c3 * D + 2 * l);
      ax = fmaf(m0.y, bf2f(x0.x), ax); ay = fmaf(m0.y, bf2f(x0.y), ay);
      ax = fmaf(m1.y, bf2f(x1.x), ax); ay = fmaf(m1.y, bf2f(x1.y), ay);
      ax = fmaf(m2.y, bf2f(x2.x), ax); ay = fmaf(m2.y, bf2f(x2.y), ay);
      ax = fmaf(m3.y, bf2f(x3.x), ax); ay = fmaf(m3.y, bf2f(x3.y), ay);
    }
    for (; j < e; ++j) {
      float2 m = sorted[j];
      int c = __float_as_int(m.x) & 0x1FFFF;
      ushort2 x = *(const ushort2*)(H2 + (size_t)c * D + 2 * l);
      ax = fmaf(m.y, bf2f(x.x), ax); ay = fmaf(m.y, bf2f(x.y), ay);
    }
    ax = ax >= 0.f ? ax : 0.2f * ax;
    ay = ay >= 0.f ? ay : 0.2f * ay;
    float2 o;
    o.x = ax;
    o.y = ay;
    ((float2*)(out + (size_t)row * D))[l] = o;
  }
}

// ---------------------------------------------------------------------------
// Fallback path (fp32 H + atomic scatter) if workspace/shape limits exceeded.
// ---------------------------------------------------------------------------
__global__ __launch_bounds__(256) void gemm_mfma_f32_kernel(
    const float* __restrict__ emb, const float* __restrict__ W,
    float* __restrict__ H, int N) {
  __shared__ short8 WldsV[2048];
  char* Wlds = (char*)WldsV;
  const int tid = threadIdx.x;
  for (int i = tid; i < 128 * 16; i += 256) {
    int o = i >> 4, dblk = i & 15;
    const float* wp = W + o * D + dblk * 8;
    float4 f0 = *(const float4*)wp;
    float4 f1 = *(const float4*)(wp + 4);
    short8 u;
    u[0] = f2bf(f0.x); u[1] = f2bf(f0.y); u[2] = f2bf(f0.z); u[3] = f2bf(f0.w);
    u[4] = f2bf(f1.x); u[5] = f2bf(f1.y); u[6] = f2bf(f1.z); u[7] = f2bf(f1.w);
    *(short8*)(Wlds + o * 256 + ((dblk ^ (o & 7)) << 4)) = u;
  }
  __syncthreads();
  const int w = tid >> 6, l = tid & 63;
  const int lo = l & 15, hi = l >> 4;
  const int mbase = blockIdx.x * 64 + w * 16;
  int arow = mbase + lo;
  if (arow >= N) arow = N - 1;
  const float* ap = emb + (size_t)arow * D + hi * 8;
  float4 a0[4], a1[4];
#pragma unroll
  for (int kb = 0; kb < 4; ++kb) {
    a0[kb] = *(const float4*)(ap + kb * 32);
    a1[kb] = *(const float4*)(ap + kb * 32 + 4);
  }
  f32x4 acc[8];
#pragma unroll
  for (int ot = 0; ot < 8; ++ot) acc[ot] = (f32x4){0.f, 0.f, 0.f, 0.f};
  const char* brow = Wlds + lo * 256;
#pragma unroll
  for (int kb = 0; kb < 4; ++kb) {
    short8 av;
    av[0] = f2bf(a0[kb].x); av[1] = f2bf(a0[kb].y);
    av[2] = f2bf(a0[kb].z); av[3] = f2bf(a0[kb].w);
    av[4] = f2bf(a1[kb].x); av[5] = f2bf(a1[kb].y);
    av[6] = f2bf(a1[kb].z); av[7] = f2bf(a1[kb].w);
    const int xb = (((kb << 2) | hi) ^ (l & 7)) << 4;
#pragma unroll
    for (int ot = 0; ot < 8; ++ot) {
      short8 bv = *(const short8*)(brow + ot * 4096 + xb);
      acc[ot] = __builtin_amdgcn_mfma_f32_16x16x32_bf16(av, bv, acc[ot], 0, 0, 0);
    }
  }
  const int rowout = mbase + hi * 4;
#pragma unroll
  for (int r = 0; r < 4; ++r) {
    int ro = rowout + r;
    if (ro < N) {
      float* op = H + (size_t)ro * D + lo;
#pragma unroll
      for (int ot = 0; ot < 8; ++ot) op[ot * 16] = acc[ot][r];
    }
  }
}

__global__ __launch_bounds__(256) void spmm_scatter_kernel(
    const float* __restrict__ H, const int* __restrict__ rows,
    const int* __restrict__ cols, const float* __restrict__ vals,
    float* __restrict__ out, int E) {
  long long gid = (long long)blockIdx.x * blockDim.x + threadIdx.x;
  int e = (int)(gid >> 5);
  int l = (int)(gid & 31);
  if (e >= E) return;
  int r = rows[e];
  int c = cols[e];
  float v = vals[e];
  float4 h4 = ((const float4*)(H + (size_t)c * D))[l];
  float* op = out + (size_t)r * D + l * 4;
  atomicAdd(op + 0, v * h4.x);
  atomicAdd(op + 1, v * h4.y);
  atomicAdd(op + 2, v * h4.z);
  atomicAdd(op + 3, v * h4.w);
}

__global__ __launch_bounds__(256) void leaky_kernel(float* __restrict__ out,
                                                    int n4) {
  for (int i = blockIdx.x * blockDim.x + threadIdx.x; i < n4;
       i += gridDim.x * blockDim.x) {
    float4 v = ((const float4*)out)[i];
    v.x = v.x >= 0.f ? v.x : 0.2f * v.x;
    v.y = v.y >= 0.f ? v.y : 0.2f * v.y;
    v.z = v.z >= 0.f ? v.z : 0.2f * v.z;
    v.w = v.w >= 0.f ? v.w : 0.2f * v.w;
    ((float4*)out)[i] = v;
  }
}

extern "C" void kernel_launch(void* const* d_in, const int* in_sizes, int n_in,
                              void* d_out, int out_size, void* d_ws,
                              size_t ws_size, hipStream_t stream) {
  const float* emb  = (const float*)d_in[0];
  const float* W    = (const float*)d_in[1];
  const int*   rows = (const int*)d_in[2];
  const int*   cols = (const int*)d_in[3];
  const float* vals = (const float*)d_in[4];
  float* out = (float*)d_out;

  int N = in_sizes[0] / D;
  int E = in_sizes[2];
  int npart = (N + PROWS - 1) / PROWS;

  char* p = (char*)d_ws;
  auto carve = [&](size_t bytes) {
    char* r = p;
    p += (bytes + 255) & ~(size_t)255;
    return r;
  };
  unsigned short* H2     = (unsigned short*)carve((size_t)N * D * 2);
  unsigned short* W2     = (unsigned short*)carve((size_t)D * D * 2);
  int*            cursor = (int*)carve((size_t)npart * sizeof(int));
  float2*         slots  = (float2*)carve((size_t)npart * CAP * sizeof(float2));
  size_t needed = (size_t)(p - (char*)d_ws);

  int gblocks = (N + 63) / 64;
  int nb_edge = (E + 256 * PASSA_EPT - 1) / (256 * PASSA_EPT);

  if (needed <= ws_size && npart <= NPART_MAX && N <= (1 << 17)) {
    int pb = ((D * D > npart ? D * D : npart) + 255) / 256;
    prep_kernel<<<pb, 256, 0, stream>>>(W, W2, cursor, npart);
    fused_gemm_scatter_kernel<<<nb_edge + gblocks, 256, 0, stream>>>(
        emb, W2, H2, rows, cols, vals, cursor, slots, E, N, npart, nb_edge);
    spmm_part_kernel<<<npart, 256, 0, stream>>>(H2, cursor, slots, out, N);
  } else {
    float* Hf = (float*)d_ws;
    gemm_mfma_f32_kernel<<<gblocks, 256, 0, stream>>>(emb, W, Hf, N);
    hipMemsetAsync(d_out, 0, (size_t)N * D * sizeof(float), stream);
    long long sthreads = (long long)E * 32;
    int sblocks = (int)((sthreads + 255) / 256);
    spmm_scatter_kernel<<<sblocks, 256, 0, stream>>>(Hf, rows, cols, vals, out, E);
    leaky_kernel<<<1024, 256, 0, stream>>>(out, N * D / 4);
  }
}